// Round 16
// baseline (2607.377 us; speedup 1.0000x reference)
//
#include <hip/hip_runtime.h>
#include <stdint.h>

#define TT 128

typedef __attribute__((ext_vector_type(8))) short short8;
typedef __attribute__((ext_vector_type(4))) float f32x4;
typedef __attribute__((ext_vector_type(4))) uint32_t u32x4;

__device__ __forceinline__ float blo(uint32_t u){ union{uint32_t i; float f;} v; v.i = u << 16; return v.f; }
__device__ __forceinline__ float bhi(uint32_t u){ union{uint32_t i; float f;} v; v.i = u & 0xffff0000u; return v.f; }
__device__ __forceinline__ float bf2f(uint16_t u){ union{uint32_t i; float f;} v; v.i = ((uint32_t)u) << 16; return v.f; }
__device__ __forceinline__ uint16_t f2bf(float f){
  union{float f; uint32_t i;} v; v.f = f;
  uint32_t r = v.i + 0x7fffu + ((v.i >> 16) & 1u);
  return (uint16_t)(r >> 16);
}
__device__ __forceinline__ uint32_t bfpack(float a, float b) {
  return (uint32_t)f2bf(a) | ((uint32_t)f2bf(b) << 16);
}
// cache-bypassing exchange ops (agent scope, relaxed — NO cache-wide fences)
__device__ __forceinline__ void xstore(uint32_t* p, uint32_t v) {
  __hip_atomic_store(p, v, __ATOMIC_RELAXED, __HIP_MEMORY_SCOPE_AGENT);
}
__device__ __forceinline__ uint32_t xload(const uint32_t* p) {
  return __hip_atomic_load(p, __ATOMIC_RELAXED, __HIP_MEMORY_SCOPE_AGENT);
}
__device__ __forceinline__ void xstore64(unsigned long long* p, unsigned long long v) {
  __hip_atomic_store(p, v, __ATOMIC_RELAXED, __HIP_MEMORY_SCOPE_AGENT);
}
__device__ __forceinline__ unsigned long long xload64(const unsigned long long* p) {
  return __hip_atomic_load(p, __ATOMIC_RELAXED, __HIP_MEMORY_SCOPE_AGENT);
}
__device__ __forceinline__ void xstoref(float* p, float v) {
  __hip_atomic_store(p, v, __ATOMIC_RELAXED, __HIP_MEMORY_SCOPE_AGENT);
}
__device__ __forceinline__ float xloadf(const float* p) {
  return __hip_atomic_load(p, __ATOMIC_RELAXED, __HIP_MEMORY_SCOPE_AGENT);
}

// ---------------- prep kernels ----------------
__global__ __launch_bounds__(256) void k_prep_mem(const float* __restrict__ mem,
                                                  uint32_t* __restrict__ memK,
                                                  uint32_t* __restrict__ memT) {
  int idx = blockIdx.x * 256 + threadIdx.x;   // 2 * 32*256*256
  if (idx < 2097152) {
    int e2 = idx & 255, k = (idx >> 8) & 255, b = idx >> 16;
    const float* p = mem + ((size_t)(b * 256 + k)) * 512 + e2 * 2;
    memK[idx] = bfpack(p[0], p[1]);
  } else {
    int j = idx - 2097152;
    int k = j & 255, e2 = (j >> 8) & 255, b = j >> 16;
    const float* p = mem + ((size_t)(b * 256 + k)) * 512 + e2 * 2;
    memT[j] = bfpack(p[0], p[1]);
  }
}

// 16-slice gate weights (same as R15): idx = sg*65536 + kc*512 + t2*4 + kk,
// gate row j = (t2&3)*512 + 32*sg + (t2>>2); k0 = kc*8 + kk*2.
__global__ __launch_bounds__(256) void k_prep_wsl2(const float* __restrict__ W_ih, const float* __restrict__ W_hh,
                                                   uint32_t* __restrict__ Wsl2) {
  int idx = blockIdx.x * 256 + threadIdx.x;   // 1048576
  int kk = idx & 3, t2 = (idx >> 2) & 127, kc = (idx >> 9) & 127, sg = idx >> 16;
  int j = (t2 & 3) * 512 + sg * 32 + (t2 >> 2);
  int k0 = kc * 8 + kk * 2;
  float w0 = (k0 < 512) ? W_ih[(size_t)j * 1024 + k0] : W_hh[(size_t)j * 512 + (k0 - 512)];
  float w1 = (k0 + 1 < 512) ? W_ih[(size_t)j * 1024 + k0 + 1] : W_hh[(size_t)j * 512 + (k0 + 1 - 512)];
  Wsl2[idx] = bfpack(w0, w1);
}

__global__ __launch_bounds__(256) void k_prep_wx(const float* __restrict__ W_ih,
                                                 const float* __restrict__ b_ih, const float* __restrict__ b_hh,
                                                 uint16_t* __restrict__ Wxp, float* __restrict__ biasp) {
  int idx = blockIdx.x * 256 + threadIdx.x;   // 2048*512
  int k = idx & 511, j = idx >> 9;
  Wxp[idx] = f2bf(W_ih[(size_t)j * 1024 + 512 + k]);
  if (k == 0) biasp[j] = b_ih[j] + b_hh[j];
}

__global__ __launch_bounds__(256) void k_prep_wo(const float* __restrict__ W_out, uint16_t* __restrict__ WoP) {
  int idx = blockIdx.x * 256 + threadIdx.x;   // 10112*512 (pad rows zeroed)
  if (idx < 5120000) WoP[idx] = f2bf(W_out[idx]);
  else WoP[idx] = 0;
}

__global__ __launch_bounds__(256) void k_gather_x(const float* __restrict__ emb, const int* __restrict__ tgt,
                                                  uint16_t* __restrict__ Axg) {
  int idx = blockIdx.x * 256 + threadIdx.x;   // 4096*512
  int k = idx & 511, m = idx >> 9;
  Axg[idx] = f2bf(emb[(size_t)tgt[m] * 512 + k]);
}

// ---------------- bf16 MFMA GEMM (unchanged) ----------------
template<int MODE>
__global__ __launch_bounds__(256) void gemm_bt(const uint16_t* __restrict__ A, const uint16_t* __restrict__ B,
                                               const float* __restrict__ bias, void* __restrict__ Cout,
                                               int K, int Nreal, int ldc, int tilesN) {
  __shared__ __align__(16) uint16_t As[128 * 32];
  __shared__ __align__(16) uint16_t Bs[128 * 32];
  const int tid = threadIdx.x;
  const int wv = tid >> 6, lane = tid & 63;
  const int tm = blockIdx.x / tilesN, tn = blockIdx.x % tilesN;
  const int wr = wv >> 1, wc = wv & 1;

  f32x4 acc[4][4];
#pragma unroll
  for (int m = 0; m < 4; ++m)
#pragma unroll
    for (int n = 0; n < 4; ++n) acc[m][n] = (f32x4){0.f, 0.f, 0.f, 0.f};

  const int frow = lane & 15;
  const int fk = (lane >> 4) << 3;
  const int srow = lane >> 2;
  const int skof = (lane & 3) << 3;

  const uint16_t* Abase = A + (size_t)tm * 128 * K;
  const uint16_t* Bbase = B + (size_t)tn * 128 * K;

  for (int k0 = 0; k0 < K; k0 += 32) {
    __syncthreads();
#pragma unroll
    for (int i = 0; i < 2; ++i) {               // 8 chunks of 16 rows = 128 rows
      const int chunk = wv * 2 + i;
      const int row = chunk * 16 + srow;
      const uint16_t* ga = Abase + (size_t)row * K + k0 + skof;
      const uint16_t* gb = Bbase + (size_t)row * K + k0 + skof;
      __builtin_amdgcn_global_load_lds((const __attribute__((address_space(1))) uint32_t*)(const void*)ga,
                                       (__attribute__((address_space(3))) uint32_t*)(void*)(As + chunk * 512),
                                       16, 0, 0);
      __builtin_amdgcn_global_load_lds((const __attribute__((address_space(1))) uint32_t*)(const void*)gb,
                                       (__attribute__((address_space(3))) uint32_t*)(void*)(Bs + chunk * 512),
                                       16, 0, 0);
    }
    __syncthreads();
    short8 af[4], bfr[4];
#pragma unroll
    for (int m = 0; m < 4; ++m) af[m] = *(const short8*)(As + (wr * 64 + m * 16 + frow) * 32 + fk);
#pragma unroll
    for (int n = 0; n < 4; ++n) bfr[n] = *(const short8*)(Bs + (wc * 64 + n * 16 + frow) * 32 + fk);
#pragma unroll
    for (int m = 0; m < 4; ++m)
#pragma unroll
      for (int n = 0; n < 4; ++n)
        acc[m][n] = __builtin_amdgcn_mfma_f32_16x16x32_bf16(af[m], bfr[n], acc[m][n], 0, 0, 0);
  }

  const int crow = (lane >> 4) << 2;
  const int ccol = lane & 15;
#pragma unroll
  for (int n = 0; n < 4; ++n) {
    const int gcol = tn * 128 + wc * 64 + n * 16 + ccol;
    if (gcol < Nreal) {
      const float bv = bias[gcol];
#pragma unroll
      for (int m = 0; m < 4; ++m) {
#pragma unroll
        for (int j = 0; j < 4; ++j) {
          const int grow = tm * 128 + wr * 64 + m * 16 + crow + j;
          const float v = acc[m][n][j] + bv;
          if (MODE == 0) ((float*)Cout)[(size_t)grow * ldc + gcol] = v;
          else {
            int q = gcol >> 9, r = gcol & 511;
            int pos = ((r >> 6) << 8) + ((r & 63) << 2) + q;
            ((uint16_t*)Cout)[(size_t)grow * ldc + pos] = f2bf(v);
          }
        }
      }
    }
  }
}

// ---------------- recurrence: 512 WGs x 256 threads, 2 WGs/CU (hardware pipelining) ----------
// R16: WG g = slice sg = (g&7)|(((g>>3)&1)<<3) of batch b = g>>4. One batch per WG, simple
// serial phase chain; TWO co-resident WGs per CU interleave at instruction granularity so
// each other's polls / MALL exchanges / L2 weight-stream latency is hidden by the hardware
// scheduler (R14 measured 1.78x per-WG efficiency from exactly this co-scheduling).
__global__ __launch_bounds__(256, 2) void recur_kernel(
    const uint32_t* __restrict__ memK, const uint32_t* __restrict__ memT,
    const uint32_t* __restrict__ Wsl2, const uint16_t* __restrict__ Xgp,
    unsigned long long* __restrict__ ugl, float* __restrict__ zgl,
    uint32_t* __restrict__ hgl, uint16_t* __restrict__ hA, uint32_t* __restrict__ flags) {
  __shared__ __align__(16) uint32_t mTl[4096];     // [e2][kl] slice of memT (16 KB)
  __shared__ __align__(16) uint32_t mKl[4096];     // [kk][e2] slice of memK (16 KB)
  __shared__ __align__(16) uint32_t hx[256];       // h pairs
  __shared__ __align__(16) float xf[1024];         // [ctx(512); h(512)] f32
  __shared__ float red[64];                        // A reduce: 4 waves x 16 keys
  __shared__ __align__(16) float accs[256];        // D reduce
  __shared__ float el[16];                         // exp(scores) of this slice's 16 keys

  const int g = blockIdx.x;                        // 0..511
  const int sg = (g & 7) | (((g >> 3) & 1) << 3);  // XCD g&7 hosts slices {x, x+8} -> L2-hot
  const int b = g >> 4;                            // batch 0..31
  const int tid = threadIdx.x;
  const int lane = tid & 63;
  const int wv = tid >> 6;                         // 0..3
  const int kl = tid & 15, eg = tid >> 4;          // A: key-local, e2-group in [0,16)
  const int t2 = tid & 127, half = tid >> 7;       // D: gate-row, k-half

  const uint32_t* wr2 = Wsl2 + ((size_t)sg << 16) + t2 * 4;
  const int rD = 32 * sg + (t2 >> 2), qD = t2 & 3;
  const int posD = ((rD >> 6) << 8) + ((rD & 63) << 2) + qD;
  uint32_t* flagsb = flags + b * 32;
  unsigned long long* ub = ugl + ((size_t)(b * 16) << 8);

  // ---- one-time staging of this WG's mem slices into LDS ----
  {
    const uint32_t* mKb = memK + ((size_t)b << 16) + ((size_t)(16 * sg) << 8);
    const uint32_t* mTb = memT + ((size_t)b << 16) + 16 * sg;
    for (int j = tid; j < 4096; j += 256) {
      mKl[j] = mKb[j];                             // [kk][e2] contiguous 16 KB
      mTl[j] = mTb[(size_t)(j >> 4) * 256 + (j & 15)];   // [e2][kl]
    }
  }
  float cS = 0.f;                                  // cell state for state 32sg + (tid>>2), tid<128
  hx[tid] = 0u;
  xf[tid] = 0.f; xf[256 + tid] = 0.f; xf[512 + tid] = 0.f; xf[768 + tid] = 0.f;
  __syncthreads();

  for (int t = 0; t < TT; ++t) {
    const int T1 = 2 * t + 1, T2 = 2 * t + 2;
    // ---- A: score for key 16sg+kl over e2 = eg+16i (LDS) ----
    {
      float sc = 0.f;
#pragma unroll
      for (int i = 0; i < 16; ++i) {
        uint32_t mw = mTl[((eg + (i << 4)) << 4) + kl];
        uint32_t hw = hx[eg + (i << 4)];
        sc = fmaf(blo(mw), blo(hw), sc);
        sc = fmaf(bhi(mw), bhi(hw), sc);
      }
      sc += __shfl_xor(sc, 16);                    // reduce the wave's 4 eg's
      sc += __shfl_xor(sc, 32);
      if (lane < 16) red[wv * 16 + lane] = sc;
    }
    __syncthreads();
    if (tid < 16) {                                // no-max softmax partials (exact in u/z ratio)
      float sf = red[tid] + red[16 + tid] + red[32 + tid] + red[48 + tid];
      float e = __expf(sf * 0.044194173824159216f);
      el[tid] = e;
      float z = e;
      z += __shfl_xor(z, 8); z += __shfl_xor(z, 4);
      z += __shfl_xor(z, 2); z += __shfl_xor(z, 1);
      if (tid == 0) xstoref(&zgl[b * 16 + sg], z);
    }
    __syncthreads();
    // ---- C': u[e2=tid] over this slice's 16 keys (LDS), publish directly ----
    {
      float ux = 0.f, uy = 0.f;
#pragma unroll
      for (int kk = 0; kk < 16; ++kk) {
        uint32_t mw = mKl[(kk << 8) + tid];
        float e = el[kk];
        ux = fmaf(blo(mw), e, ux);
        uy = fmaf(bhi(mw), e, uy);
      }
      union { float f[2]; unsigned long long u; } pk;
      pk.f[0] = ux; pk.f[1] = uy;
      xstore64(&ub[(sg << 8) + tid], pk.u);
    }
    // ---- barrier 1: u,z exchange among the batch's 16 slices ----
    __syncthreads();                               // drain u/z stores
    if (tid == 0) xstore(&flagsb[sg], (uint32_t)T1);
    if (tid < 64) {
      int v;
      do {
        __builtin_amdgcn_s_sleep(2);
        v = (tid < 16) ? (int)xload(&flagsb[tid]) : T1;
      } while (__any(v < T1));
    }
    __syncthreads();
    // ---- u,z -> ctx (thread e2 = tid sums 16 slice-partials) ----
    {
      float zsum = 0.f;
#pragma unroll
      for (int q = 0; q < 16; ++q) zsum += xloadf(&zgl[b * 16 + q]);
      float ux = 0.f, uy = 0.f;
#pragma unroll
      for (int q = 0; q < 16; ++q) {
        union { float f[2]; unsigned long long u; } pk;
        pk.u = xload64(&ub[(q << 8) + tid]);
        ux += pk.f[0]; uy += pk.f[1];
      }
      float rz = 1.f / zsum;
      xf[2 * tid] = ux * rz;
      xf[2 * tid + 1] = uy * rz;
    }
    __syncthreads();
    // ---- D: gate row j = (t2&3)*512 + 32sg + (t2>>2); k-half per thread, L2 stream ----
    {
      float acc = (half == 0) ? bf2f(Xgp[((size_t)(b * TT + t)) * 2048 + posD]) : 0.f;
      const int kc0 = half * 64;
#pragma unroll 8
      for (int j = 0; j < 64; ++j) {
        const int kc = kc0 + j;
        u32x4 w4 = *(const u32x4*)(wr2 + (size_t)kc * 512);
        f32x4 xa = *(const f32x4*)(xf + kc * 8);
        f32x4 xb = *(const f32x4*)(xf + kc * 8 + 4);
        acc = fmaf(blo(w4.x), xa.x, acc); acc = fmaf(bhi(w4.x), xa.y, acc);
        acc = fmaf(blo(w4.y), xa.z, acc); acc = fmaf(bhi(w4.y), xa.w, acc);
        acc = fmaf(blo(w4.z), xb.x, acc); acc = fmaf(bhi(w4.z), xb.y, acc);
        acc = fmaf(blo(w4.w), xb.z, acc); acc = fmaf(bhi(w4.w), xb.w, acc);
      }
      accs[tid] = acc;
    }
    __syncthreads();
    // ---- E: LSTM pointwise; quad lanes hold (i,f,g,o) of state r = 32sg + (tid>>2) ----
    if (tid < 128) {
      float tot = accs[tid] + accs[tid + 128];
      int lbase = lane & ~3;
      float gi = __shfl(tot, lbase, 64);
      float gf = __shfl(tot, lbase + 1, 64);
      float gg = __shfl(tot, lbase + 2, 64);
      float go = __shfl(tot, lbase + 3, 64);
      cS = (1.f / (1.f + __expf(-gf))) * cS + (1.f / (1.f + __expf(-gi))) * tanhf(gg);
      float hn = (1.f / (1.f + __expf(-go))) * tanhf(cS);
      float hn4 = __shfl(hn, (lane & ~7) + 4, 64);       // partner quad's h (state r+1)
      if ((tid & 7) == 0) {
        uint32_t hp = bfpack(hn, hn4);
        int r2 = 16 * sg + (tid >> 3);                   // pair index within [32sg,32sg+32)
        xstore(&hgl[(b << 8) + r2], hp);
        ((uint32_t*)hA)[((size_t)b * TT + t) * 256 + r2] = hp;
      }
    }
    // ---- barrier 2: h exchange ----
    __syncthreads();                               // drain h stores
    if (tid == 0) xstore(&flagsb[sg], (uint32_t)T2);
    if (tid < 64) {
      int v;
      do {
        __builtin_amdgcn_s_sleep(2);
        v = (tid < 16) ? (int)xload(&flagsb[tid]) : T2;
      } while (__any(v < T2));
    }
    __syncthreads();
    // ---- F: reload full h ----
    {
      uint32_t hp = xload(&hgl[(b << 8) + tid]);
      hx[tid] = hp;
      xf[512 + 2 * tid] = blo(hp);
      xf[513 + 2 * tid] = bhi(hp);
    }
    __syncthreads();
  }
}

// ---------------- launch ----------------
extern "C" void kernel_launch(void* const* d_in, const int* in_sizes, int n_in,
                              void* d_out, int out_size, void* d_ws, size_t ws_size,
                              hipStream_t stream) {
  const float* memory = (const float*)d_in[0];
  const int*   tgt    = (const int*)d_in[1];
  const float* emb_in = (const float*)d_in[2];
  const float* W_ih   = (const float*)d_in[3];
  const float* W_hh   = (const float*)d_in[4];
  const float* b_ih   = (const float*)d_in[5];
  const float* b_hh   = (const float*)d_in[6];
  const float* W_out  = (const float*)d_in[7];
  const float* b_out  = (const float*)d_in[8];
  float* out = (float*)d_out;
  char* ws = (char*)d_ws;

  uint32_t* memK  = (uint32_t*)(ws);                    // 8,388,608  [b][k][e2] bf16x2
  uint32_t* memT  = (uint32_t*)(ws + 8388608);          // 8,388,608  [b][e2][k] bf16x2
  uint32_t* Wsl2  = (uint32_t*)(ws + 16777216);         // 4,194,304  16-slice gate weights
  uint16_t* Wxp   = (uint16_t*)(ws + 20971520);         // 2,097,152  [j][512] bf16
  float*    biasp = (float*)(ws + 23068672);            // 8,192
  uint16_t* WoP   = (uint16_t*)(ws + 23076864);         // 10,354,688 [10112][512] bf16
  uint16_t* Axg   = (uint16_t*)(ws + 33431552);         // 4,194,304  [m][512] bf16 (dead after gemm<1>)
  uint16_t* Xgp   = (uint16_t*)(ws + 37625856);         // 16,777,216 [m][2048] bf16 slice-permuted
  uint16_t* hA    = (uint16_t*)(ws + 54403072);         // 4,194,304  [m][512] bf16
  uint32_t* hgl   = (uint32_t*)(ws + 58597376);         // 32,768     [b][256] bf16x2 h-exchange
  float*    zgl   = (float*)(ws + 58630144);            // 2,048      [b][16] f32 partial denominators
  uint32_t* flags = (uint32_t*)(ws + 58662912);         // 4,096      [b][32] flag array (zeroed per call)
  unsigned long long* ugl = (unsigned long long*)Axg;   // 1,048,576  [b][16][256] f32-pair partial ctx

  hipMemsetAsync(flags, 0, 4096, stream);

  k_prep_mem<<<16384, 256, 0, stream>>>(memory, memK, memT);
  k_prep_wsl2<<<4096, 256, 0, stream>>>(W_ih, W_hh, Wsl2);
  k_prep_wx<<<4096, 256, 0, stream>>>(W_ih, b_ih, b_hh, Wxp, biasp);
  k_prep_wo<<<20224, 256, 0, stream>>>(W_out, WoP);
  k_gather_x<<<8192, 256, 0, stream>>>(emb_in, tgt, Axg);

  gemm_bt<1><<<32 * 16, 256, 0, stream>>>(Axg, Wxp, biasp, Xgp, 512, 2048, 2048, 16);

  // 512 WGs x 256 threads: 2 co-resident WGs/CU, hardware-interleaved batch pipelines
  recur_kernel<<<512, 256, 0, stream>>>(memK, memT, Wsl2, Xgp, ugl, zgl, hgl, hA, flags);

  gemm_bt<0><<<32 * 79, 256, 0, stream>>>(hA, WoP, b_out, out, 512, 10000, 10000, 79);
}

// Round 17
// 1863.019 us; speedup vs baseline: 1.3995x; 1.3995x over previous
//
#include <hip/hip_runtime.h>
#include <stdint.h>

#define TT 128

typedef __attribute__((ext_vector_type(8))) short short8;
typedef __attribute__((ext_vector_type(4))) float f32x4;
typedef __attribute__((ext_vector_type(4))) uint32_t u32x4;

__device__ __forceinline__ float blo(uint32_t u){ union{uint32_t i; float f;} v; v.i = u << 16; return v.f; }
__device__ __forceinline__ float bhi(uint32_t u){ union{uint32_t i; float f;} v; v.i = u & 0xffff0000u; return v.f; }
__device__ __forceinline__ float bf2f(uint16_t u){ union{uint32_t i; float f;} v; v.i = ((uint32_t)u) << 16; return v.f; }
__device__ __forceinline__ uint16_t f2bf(float f){
  union{float f; uint32_t i;} v; v.f = f;
  uint32_t r = v.i + 0x7fffu + ((v.i >> 16) & 1u);
  return (uint16_t)(r >> 16);
}
__device__ __forceinline__ uint32_t bfpack(float a, float b) {
  return (uint32_t)f2bf(a) | ((uint32_t)f2bf(b) << 16);
}
// cache-bypassing exchange ops (agent scope, relaxed — NO cache-wide fences)
__device__ __forceinline__ void xstore(uint32_t* p, uint32_t v) {
  __hip_atomic_store(p, v, __ATOMIC_RELAXED, __HIP_MEMORY_SCOPE_AGENT);
}
__device__ __forceinline__ uint32_t xload(const uint32_t* p) {
  return __hip_atomic_load(p, __ATOMIC_RELAXED, __HIP_MEMORY_SCOPE_AGENT);
}
__device__ __forceinline__ void xstore64(unsigned long long* p, unsigned long long v) {
  __hip_atomic_store(p, v, __ATOMIC_RELAXED, __HIP_MEMORY_SCOPE_AGENT);
}
__device__ __forceinline__ unsigned long long xload64(const unsigned long long* p) {
  return __hip_atomic_load(p, __ATOMIC_RELAXED, __HIP_MEMORY_SCOPE_AGENT);
}
__device__ __forceinline__ void xstoref(float* p, float v) {
  __hip_atomic_store(p, v, __ATOMIC_RELAXED, __HIP_MEMORY_SCOPE_AGENT);
}
__device__ __forceinline__ float xloadf(const float* p) {
  return __hip_atomic_load(p, __ATOMIC_RELAXED, __HIP_MEMORY_SCOPE_AGENT);
}

// ---------------- prep kernels ----------------
__global__ __launch_bounds__(256) void k_prep_mem(const float* __restrict__ mem,
                                                  uint32_t* __restrict__ memK,
                                                  uint32_t* __restrict__ memT) {
  int idx = blockIdx.x * 256 + threadIdx.x;   // 2 * 32*256*256
  if (idx < 2097152) {
    int e2 = idx & 255, k = (idx >> 8) & 255, b = idx >> 16;
    const float* p = mem + ((size_t)(b * 256 + k)) * 512 + e2 * 2;
    memK[idx] = bfpack(p[0], p[1]);
  } else {
    int j = idx - 2097152;
    int k = j & 255, e2 = (j >> 8) & 255, b = j >> 16;
    const float* p = mem + ((size_t)(b * 256 + k)) * 512 + e2 * 2;
    memT[j] = bfpack(p[0], p[1]);
  }
}

// 16-slice gate weights: Wsl2 idx = sg*65536 + kc*512 + t2*4 + kk, where slice sg in [0,16)
// owns states [32sg,32sg+32); t2 in [0,128) <-> gate row j = (t2&3)*512 + 32*sg + (t2>>2);
// kc in [0,128) = k-chunk of 8 elements, k0 = kc*8 + kk*2.
__global__ __launch_bounds__(256) void k_prep_wsl2(const float* __restrict__ W_ih, const float* __restrict__ W_hh,
                                                   uint32_t* __restrict__ Wsl2) {
  int idx = blockIdx.x * 256 + threadIdx.x;   // 1048576
  int kk = idx & 3, t2 = (idx >> 2) & 127, kc = (idx >> 9) & 127, sg = idx >> 16;
  int j = (t2 & 3) * 512 + sg * 32 + (t2 >> 2);
  int k0 = kc * 8 + kk * 2;
  float w0 = (k0 < 512) ? W_ih[(size_t)j * 1024 + k0] : W_hh[(size_t)j * 512 + (k0 - 512)];
  float w1 = (k0 + 1 < 512) ? W_ih[(size_t)j * 1024 + k0 + 1] : W_hh[(size_t)j * 512 + (k0 + 1 - 512)];
  Wsl2[idx] = bfpack(w0, w1);
}

__global__ __launch_bounds__(256) void k_prep_wx(const float* __restrict__ W_ih,
                                                 const float* __restrict__ b_ih, const float* __restrict__ b_hh,
                                                 uint16_t* __restrict__ Wxp, float* __restrict__ biasp) {
  int idx = blockIdx.x * 256 + threadIdx.x;   // 2048*512
  int k = idx & 511, j = idx >> 9;
  Wxp[idx] = f2bf(W_ih[(size_t)j * 1024 + 512 + k]);
  if (k == 0) biasp[j] = b_ih[j] + b_hh[j];
}

__global__ __launch_bounds__(256) void k_prep_wo(const float* __restrict__ W_out, uint16_t* __restrict__ WoP) {
  int idx = blockIdx.x * 256 + threadIdx.x;   // 10112*512 (pad rows zeroed)
  if (idx < 5120000) WoP[idx] = f2bf(W_out[idx]);
  else WoP[idx] = 0;
}

__global__ __launch_bounds__(256) void k_gather_x(const float* __restrict__ emb, const int* __restrict__ tgt,
                                                  uint16_t* __restrict__ Axg) {
  int idx = blockIdx.x * 256 + threadIdx.x;   // 4096*512
  int k = idx & 511, m = idx >> 9;
  Axg[idx] = f2bf(emb[(size_t)tgt[m] * 512 + k]);
}

// ---------------- bf16 MFMA GEMM ----------------
template<int MODE>
__global__ __launch_bounds__(256) void gemm_bt(const uint16_t* __restrict__ A, const uint16_t* __restrict__ B,
                                               const float* __restrict__ bias, void* __restrict__ Cout,
                                               int K, int Nreal, int ldc, int tilesN) {
  __shared__ __align__(16) uint16_t As[128 * 32];
  __shared__ __align__(16) uint16_t Bs[128 * 32];
  const int tid = threadIdx.x;
  const int wv = tid >> 6, lane = tid & 63;
  const int tm = blockIdx.x / tilesN, tn = blockIdx.x % tilesN;
  const int wr = wv >> 1, wc = wv & 1;

  f32x4 acc[4][4];
#pragma unroll
  for (int m = 0; m < 4; ++m)
#pragma unroll
    for (int n = 0; n < 4; ++n) acc[m][n] = (f32x4){0.f, 0.f, 0.f, 0.f};

  const int frow = lane & 15;
  const int fk = (lane >> 4) << 3;
  const int srow = lane >> 2;
  const int skof = (lane & 3) << 3;

  const uint16_t* Abase = A + (size_t)tm * 128 * K;
  const uint16_t* Bbase = B + (size_t)tn * 128 * K;

  for (int k0 = 0; k0 < K; k0 += 32) {
    __syncthreads();
#pragma unroll
    for (int i = 0; i < 2; ++i) {               // 8 chunks of 16 rows = 128 rows
      const int chunk = wv * 2 + i;
      const int row = chunk * 16 + srow;
      const uint16_t* ga = Abase + (size_t)row * K + k0 + skof;
      const uint16_t* gb = Bbase + (size_t)row * K + k0 + skof;
      __builtin_amdgcn_global_load_lds((const __attribute__((address_space(1))) uint32_t*)(const void*)ga,
                                       (__attribute__((address_space(3))) uint32_t*)(void*)(As + chunk * 512),
                                       16, 0, 0);
      __builtin_amdgcn_global_load_lds((const __attribute__((address_space(1))) uint32_t*)(const void*)gb,
                                       (__attribute__((address_space(3))) uint32_t*)(void*)(Bs + chunk * 512),
                                       16, 0, 0);
    }
    __syncthreads();
    short8 af[4], bfr[4];
#pragma unroll
    for (int m = 0; m < 4; ++m) af[m] = *(const short8*)(As + (wr * 64 + m * 16 + frow) * 32 + fk);
#pragma unroll
    for (int n = 0; n < 4; ++n) bfr[n] = *(const short8*)(Bs + (wc * 64 + n * 16 + frow) * 32 + fk);
#pragma unroll
    for (int m = 0; m < 4; ++m)
#pragma unroll
      for (int n = 0; n < 4; ++n)
        acc[m][n] = __builtin_amdgcn_mfma_f32_16x16x32_bf16(af[m], bfr[n], acc[m][n], 0, 0, 0);
  }

  const int crow = (lane >> 4) << 2;
  const int ccol = lane & 15;
#pragma unroll
  for (int n = 0; n < 4; ++n) {
    const int gcol = tn * 128 + wc * 64 + n * 16 + ccol;
    if (gcol < Nreal) {
      const float bv = bias[gcol];
#pragma unroll
      for (int m = 0; m < 4; ++m) {
#pragma unroll
        for (int j = 0; j < 4; ++j) {
          const int grow = tm * 128 + wr * 64 + m * 16 + crow + j;
          const float v = acc[m][n][j] + bv;
          if (MODE == 0) ((float*)Cout)[(size_t)grow * ldc + gcol] = v;
          else {
            int q = gcol >> 9, r = gcol & 511;
            int pos = ((r >> 6) << 8) + ((r & 63) << 2) + q;
            ((uint16_t*)Cout)[(size_t)grow * ldc + pos] = f2bf(v);
          }
        }
      }
    }
  }
}

// ---------------- recurrence: 256 WGs x 512 threads, 16 slices x dual-batch + fused D ----------
// R17 = R15 (proven best: 1866 us total). WG(g) = slice sg=g&15 of batches {pp, pp+16}.
// Stage pipeline PRE(b0) PRE(b1) POST-fused FIN(b0) FIN(b1); fused D loads each weight once
// for both batches.
__global__ __launch_bounds__(512, 1) void recur_kernel(
    const uint32_t* __restrict__ memK, const uint32_t* __restrict__ memT,
    const uint32_t* __restrict__ Wsl2, const uint16_t* __restrict__ Xgp,
    unsigned long long* __restrict__ ugl, float* __restrict__ zgl,
    uint32_t* __restrict__ hgl, uint16_t* __restrict__ hA, uint32_t* __restrict__ flags) {
  __shared__ __align__(16) uint32_t hx[2][256];    // h pairs per batch
  __shared__ __align__(16) float xf[2][1024];      // [ctx(512); h(512)] f32 per batch
  __shared__ float red[128];                       // A reduce: 8 waves x 16 keys
  __shared__ float rux[512], ruy[512];             // C' / u-read reduce
  __shared__ float accsA[512], accsB[512];         // fused-D reduce
  __shared__ float el[16];                         // exp(scores) of this slice's 16 keys

  const int g = blockIdx.x;                        // 0..255
  const int sg = g & 15, pp = g >> 4;              // XCD = g&7 (slices sg, sg+8 share XCD)
  const int b0 = pp, b1 = pp + 16;
  const int tid = threadIdx.x;
  const int lane = tid & 63;
  const int wv = tid >> 6;                         // 0..7
  const int kl = tid & 15, eg = tid >> 4;          // A: key-local kl, e2-group eg in [0,32)
  const int row = tid & 255, half = tid >> 8;      // C'/u-read split
  const int t2 = tid & 127, h4 = tid >> 7;         // D: gate-row t2, k-quarter h4

  const uint32_t* wr2 = Wsl2 + ((size_t)sg << 16) + t2 * 4;
  const int rD = 32 * sg + (t2 >> 2), qD = t2 & 3;
  const int posD = ((rD >> 6) << 8) + ((rD & 63) << 2) + qD;

  float cS = 0.f;                                  // cell state for (bi=tid>>7, state (tid&127)>>2), tid<256
  if (tid < 256) { hx[0][tid] = 0u; hx[1][tid] = 0u; }
  xf[0][tid] = 0.f; xf[0][512 + tid] = 0.f;
  xf[1][tid] = 0.f; xf[1][512 + tid] = 0.f;
  __syncthreads();

  for (int t = 0; t < TT; ++t) {
    const int T1 = 2 * t + 1, T2 = 2 * t + 2;
    // ======== PRE(b0), PRE(b1): scores + softmax partials + u publish ========
#pragma unroll
    for (int bi = 0; bi < 2; ++bi) {
      const int b = bi ? b1 : b0;
      // A: score for key 16sg+kl over e2 = eg+32i
      {
        const uint32_t* mA = memT + ((size_t)b << 16) + 16 * sg + kl;
        float sc = 0.f;
#pragma unroll
        for (int i = 0; i < 8; ++i) {
          uint32_t mw = mA[(size_t)(eg + (i << 5)) << 8];
          uint32_t hw = hx[bi][eg + (i << 5)];
          sc = fmaf(blo(mw), blo(hw), sc);
          sc = fmaf(bhi(mw), bhi(hw), sc);
        }
        sc += __shfl_xor(sc, 16);                  // reduce the 4 eg's within the wave
        sc += __shfl_xor(sc, 32);
        if (lane < 16) red[wv * 16 + lane] = sc;
      }
      __syncthreads();
      if (tid < 16) {                              // no-max softmax partials (exact in u/z ratio)
        float sf = 0.f;
#pragma unroll
        for (int w = 0; w < 8; ++w) sf += red[w * 16 + tid];
        float e = __expf(sf * 0.044194173824159216f);
        el[tid] = e;
        float z = e;
        z += __shfl_xor(z, 8); z += __shfl_xor(z, 4);
        z += __shfl_xor(z, 2); z += __shfl_xor(z, 1);
        if (tid == 0) xstoref(&zgl[b * 16 + sg], z);
      }
      __syncthreads();
      // C': partial u[e2=row] over this slice's 16 keys (half-split: 8 each)
      {
        const uint32_t* mC = memK + ((size_t)b << 16) + ((size_t)(16 * sg) << 8) + row;
        float ux = 0.f, uy = 0.f;
        const int k0 = half * 8;
#pragma unroll
        for (int kk = 0; kk < 8; ++kk) {
          uint32_t mw = mC[(size_t)(k0 + kk) << 8];
          float e = el[k0 + kk];
          ux = fmaf(blo(mw), e, ux);
          uy = fmaf(bhi(mw), e, uy);
        }
        rux[tid] = ux; ruy[tid] = uy;
      }
      __syncthreads();
      if (tid < 256) {
        union { float f[2]; unsigned long long u; } pk;
        pk.f[0] = rux[tid] + rux[tid + 256];
        pk.f[1] = ruy[tid] + ruy[tid + 256];
        xstore64(&ugl[(((size_t)b * 16 + sg) << 8) + tid], pk.u);
      }
      __syncthreads();                             // drain u/z stores
      if (tid == 0) xstore(&flags[b * 32 + sg], (uint32_t)T1);
    }
    // ======== POST (fused): ctx both batches, fused gate GEMV, LSTM both ========
#pragma unroll
    for (int bi = 0; bi < 2; ++bi) {
      const int b = bi ? b1 : b0;
      if (tid < 64) {                              // poll barrier 1 (b1's poll hides under b0's ctx)
        int v;
        do {
          __builtin_amdgcn_s_sleep(2);
          v = (tid < 16) ? (int)xload(&flags[b * 32 + tid]) : T1;
        } while (__any(v < T1));
      }
      __syncthreads();
      {
        float zsum = 0.f;
        if (tid < 256) {
#pragma unroll
          for (int q = 0; q < 16; ++q) zsum += xloadf(&zgl[b * 16 + q]);
        }
        float ux = 0.f, uy = 0.f;
        const int q0 = half * 8;
#pragma unroll
        for (int q = 0; q < 8; ++q) {
          union { float f[2]; unsigned long long u; } pk;
          pk.u = xload64(&ugl[(((size_t)b * 16 + q0 + q) << 8) + row]);
          ux += pk.f[0]; uy += pk.f[1];
        }
        rux[tid] = ux; ruy[tid] = uy;
        __syncthreads();
        if (tid < 256) {
          float rz = 1.f / zsum;
          xf[bi][2 * tid]     = (rux[tid] + rux[tid + 256]) * rz;
          xf[bi][2 * tid + 1] = (ruy[tid] + ruy[tid + 256]) * rz;
        }
      }
      __syncthreads();
    }
    // fused D: each weight load serves BOTH batches
    {
      float accA = (h4 == 0) ? bf2f(Xgp[((size_t)(b0 * TT + t)) * 2048 + posD]) : 0.f;
      float accB = (h4 == 0) ? bf2f(Xgp[((size_t)(b1 * TT + t)) * 2048 + posD]) : 0.f;
      const int kc0 = h4 * 32;
#pragma unroll 8
      for (int j = 0; j < 32; ++j) {
        const int kc = kc0 + j;
        u32x4 w4 = *(const u32x4*)(wr2 + (size_t)kc * 512);
        f32x4 xa = *(const f32x4*)(xf[0] + kc * 8);
        f32x4 xb = *(const f32x4*)(xf[0] + kc * 8 + 4);
        accA = fmaf(blo(w4.x), xa.x, accA); accA = fmaf(bhi(w4.x), xa.y, accA);
        accA = fmaf(blo(w4.y), xa.z, accA); accA = fmaf(bhi(w4.y), xa.w, accA);
        accA = fmaf(blo(w4.z), xb.x, accA); accA = fmaf(bhi(w4.z), xb.y, accA);
        accA = fmaf(blo(w4.w), xb.z, accA); accA = fmaf(bhi(w4.w), xb.w, accA);
        f32x4 ya = *(const f32x4*)(xf[1] + kc * 8);
        f32x4 yb = *(const f32x4*)(xf[1] + kc * 8 + 4);
        accB = fmaf(blo(w4.x), ya.x, accB); accB = fmaf(bhi(w4.x), ya.y, accB);
        accB = fmaf(blo(w4.y), ya.z, accB); accB = fmaf(bhi(w4.y), ya.w, accB);
        accB = fmaf(blo(w4.z), yb.x, accB); accB = fmaf(bhi(w4.z), yb.y, accB);
        accB = fmaf(blo(w4.w), yb.z, accB); accB = fmaf(bhi(w4.w), yb.w, accB);
      }
      accsA[tid] = accA; accsB[tid] = accB;
    }
    __syncthreads();
    // E: LSTM pointwise for both batches; tid<256: bi=tid>>7, row t2e=tid&127,
    // quad lanes hold (i,f,g,o) of state r = 32sg + (t2e>>2)
    if (tid < 256) {
      const int bi = tid >> 7, t2e = tid & 127;
      const int b = bi ? b1 : b0;
      float tot = bi ? (accsB[t2e] + accsB[t2e + 128] + accsB[t2e + 256] + accsB[t2e + 384])
                     : (accsA[t2e] + accsA[t2e + 128] + accsA[t2e + 256] + accsA[t2e + 384]);
      int lbase = lane & ~3;
      float gi = __shfl(tot, lbase, 64);
      float gf = __shfl(tot, lbase + 1, 64);
      float gg = __shfl(tot, lbase + 2, 64);
      float go = __shfl(tot, lbase + 3, 64);
      cS = (1.f / (1.f + __expf(-gf))) * cS + (1.f / (1.f + __expf(-gi))) * tanhf(gg);
      float hn = (1.f / (1.f + __expf(-go))) * tanhf(cS);
      float hn4 = __shfl(hn, (lane & ~7) + 4, 64);       // partner quad's h (state r+1)
      if ((tid & 7) == 0) {
        uint32_t hp = bfpack(hn, hn4);
        int r2 = 16 * sg + (t2e >> 3);                   // pair index within [32sg,32sg+32)
        xstore(&hgl[(b << 8) + r2], hp);
        ((uint32_t*)hA)[((size_t)b * TT + t) * 256 + r2] = hp;
      }
    }
    __syncthreads();                               // drain h stores of both batches
    if (tid == 0) {
      xstore(&flags[b0 * 32 + sg], (uint32_t)T2);
      xstore(&flags[b1 * 32 + sg], (uint32_t)T2);
    }
    // ======== FIN(b0), FIN(b1): poll h, reload ========
#pragma unroll
    for (int bi = 0; bi < 2; ++bi) {
      const int b = bi ? b1 : b0;
      if (tid < 64) {
        int v;
        do {
          __builtin_amdgcn_s_sleep(2);
          v = (tid < 16) ? (int)xload(&flags[b * 32 + tid]) : T2;
        } while (__any(v < T2));
      }
      __syncthreads();
      if (tid < 256) {
        uint32_t hp = xload(&hgl[(b << 8) + tid]);
        hx[bi][tid] = hp;
        xf[bi][512 + 2 * tid] = blo(hp);
        xf[bi][513 + 2 * tid] = bhi(hp);
      }
      __syncthreads();
    }
  }
}

// ---------------- launch ----------------
extern "C" void kernel_launch(void* const* d_in, const int* in_sizes, int n_in,
                              void* d_out, int out_size, void* d_ws, size_t ws_size,
                              hipStream_t stream) {
  const float* memory = (const float*)d_in[0];
  const int*   tgt    = (const int*)d_in[1];
  const float* emb_in = (const float*)d_in[2];
  const float* W_ih   = (const float*)d_in[3];
  const float* W_hh   = (const float*)d_in[4];
  const float* b_ih   = (const float*)d_in[5];
  const float* b_hh   = (const float*)d_in[6];
  const float* W_out  = (const float*)d_in[7];
  const float* b_out  = (const float*)d_in[8];
  float* out = (float*)d_out;
  char* ws = (char*)d_ws;

  uint32_t* memK  = (uint32_t*)(ws);                    // 8,388,608  [b][k][e2] bf16x2
  uint32_t* memT  = (uint32_t*)(ws + 8388608);          // 8,388,608  [b][e2][k] bf16x2
  uint32_t* Wsl2  = (uint32_t*)(ws + 16777216);         // 4,194,304  16-slice gate weights
  uint16_t* Wxp   = (uint16_t*)(ws + 20971520);         // 2,097,152  [j][512] bf16
  float*    biasp = (float*)(ws + 23068672);            // 8,192
  uint16_t* WoP   = (uint16_t*)(ws + 23076864);         // 10,354,688 [10112][512] bf16
  uint16_t* Axg   = (uint16_t*)(ws + 33431552);         // 4,194,304  [m][512] bf16 (dead after gemm<1>)
  uint16_t* Xgp   = (uint16_t*)(ws + 37625856);         // 16,777,216 [m][2048] bf16 slice-permuted
  uint16_t* hA    = (uint16_t*)(ws + 54403072);         // 4,194,304  [m][512] bf16
  uint32_t* hgl   = (uint32_t*)(ws + 58597376);         // 32,768     [b][256] bf16x2 h-exchange
  float*    zgl   = (float*)(ws + 58630144);            // 2,048      [b][16] f32 partial denominators
  uint32_t* flags = (uint32_t*)(ws + 58662912);         // 4,096      [b][32] flag array (zeroed per call)
  unsigned long long* ugl = (unsigned long long*)Axg;   // 1,048,576  [b][16][256] f32-pair partial ctx

  hipMemsetAsync(flags, 0, 4096, stream);

  k_prep_mem<<<16384, 256, 0, stream>>>(memory, memK, memT);
  k_prep_wsl2<<<4096, 256, 0, stream>>>(W_ih, W_hh, Wsl2);
  k_prep_wx<<<4096, 256, 0, stream>>>(W_ih, b_ih, b_hh, Wxp, biasp);
  k_prep_wo<<<20224, 256, 0, stream>>>(W_out, WoP);
  k_gather_x<<<8192, 256, 0, stream>>>(emb_in, tgt, Axg);

  gemm_bt<1><<<32 * 16, 256, 0, stream>>>(Axg, Wxp, biasp, Xgp, 512, 2048, 2048, 16);

  // 16-slice dual-batch pipelined recurrence on all 256 CUs, fused-D weight sharing
  recur_kernel<<<256, 512, 0, stream>>>(memK, memT, Wsl2, Xgp, ugl, zgl, hgl, hA, flags);

  gemm_bt<0><<<32 * 79, 256, 0, stream>>>(hA, WoP, b_out, out, 512, 10000, 10000, 79);
}